// Round 8
// baseline (2120.153 us; speedup 1.0000x reference)
//
#include <hip/hip_runtime.h>
#include <hip/hip_bf16.h>

// Flow-matching MLP ODE, 32 midpoint-t Euler steps.
// R6 (second resubmit; two consecutive infra failures, never measured):
// 1024-thr blocks (16 waves, 4 waves/SIMD) for cross-wave pipe overlap
// (R5 counters showed MFMA/VALU/LDS pipes fully serialized at 2 waves/SIMD).
// Register slimming to fit 128-reg budget without losing 32-row/wave economics:
//  - y-state: y = x/dt lives IN the layer-3 accumulator; W1x frags pre-scaled
//    by dt (=2^-5, exact in bf16) so b1f = bf16(y) directly. xr eliminated.
//  - single accumulator chains; w3/t1 frags loaded just-in-time.
// Weights as A-frags (32x32x16 bf16), activations as B-frags; batch col =
// lane&31 lane-resident; C->B via v_cvt_pk_bf16_f32 + v_permlane32_swap_b32.
// W2+W1 frags in 160KB LDS; W3/t1/b2/b3 from global (L1/L2-hot).

typedef __attribute__((ext_vector_type(8)))  short s16x8;   // 8 bf16 (4 VGPR)
typedef __attribute__((ext_vector_type(16))) float f32x16;  // MFMA acc
typedef __attribute__((ext_vector_type(4)))  float f32x4;

union FragU { s16x8 v; unsigned u[4]; };

__device__ __forceinline__ unsigned cvtpk_bf16(float lo, float hi){
  unsigned r;
  asm("v_cvt_pk_bf16_f32 %0, %1, %2" : "=v"(r) : "v"(lo), "v"(hi));
  return r;
}
__device__ __forceinline__ void plswap32(unsigned &a, unsigned &b){
  asm("v_permlane32_swap_b32 %0, %1" : "+v"(a), "+v"(b));
}

// C-tile (acc layout n=(r&3)+8*(r>>2)+4*g, m=l&31) -> two next-layer B-frags.
__device__ __forceinline__ void c_to_b(const f32x16 c, s16x8 &f0, s16x8 &f1){
  unsigned p0 = cvtpk_bf16(c[0],  c[1]);
  unsigned p1 = cvtpk_bf16(c[2],  c[3]);
  unsigned p2 = cvtpk_bf16(c[4],  c[5]);
  unsigned p3 = cvtpk_bf16(c[6],  c[7]);
  plswap32(p0, p2); plswap32(p1, p3);
  FragU a; a.u[0]=p0; a.u[1]=p1; a.u[2]=p2; a.u[3]=p3; f0 = a.v;
  unsigned q0 = cvtpk_bf16(c[8],  c[9]);
  unsigned q1 = cvtpk_bf16(c[10], c[11]);
  unsigned q2 = cvtpk_bf16(c[12], c[13]);
  plswap32(q0, q2);
  unsigned q1b = cvtpk_bf16(c[14], c[15]);
  plswap32(q1, q1b);
  FragU b; b.u[0]=q0; b.u[1]=q1; b.u[2]=q2; b.u[3]=q1b; f1 = b.v;
}

__device__ __forceinline__ void silu16(f32x16 &x){
#pragma unroll
  for (int i = 0; i < 16; i++){
    float e = __builtin_amdgcn_exp2f(x[i] * -1.44269504088896f); // exp(-x)
    x[i] = x[i] * __builtin_amdgcn_rcpf(1.0f + e);
  }
}

// ---- setup: pack weights + t1 frags (bf16 A-fragment images) into d_ws ----
// frag(Mt,Kt): lane l holds WT[Mt*32 + (l&31)][Kt*16 + 8*(l>>5) + j], j=0..7
// W1x frags are PRE-SCALED by dt = 1/32 (exact exponent shift) so the kernel
// can feed y = x/dt directly as the layer-1 B-operand.
// ws shorts: [0,65536) W2 frags. [65536,81920) W1x*dt. [81920,98304) W3.
//            [98304,102400) t1-frags (k0=W1[64] t-row, k1=b1).
__global__ void setup_kernel(const float* __restrict__ W1,
                             const float* __restrict__ b1,
                             const float* __restrict__ W2,
                             const float* __restrict__ W3,
                             short* __restrict__ ws){
  const int f = blockIdx.x;
  const int l = threadIdx.x;
  const int g = l >> 5, col = l & 31;

  if (f < 192){
    const float* src; int N, Mt, Kt; short* dst; float scale = 1.0f;
    if (f < 128)      { Mt = f >> 4;      Kt = f & 15;       src = W2; N = 256; dst = ws + f*512; }
    else if (f < 160) { int id = f - 128; Mt = id >> 2; Kt = id & 3;  src = W1; N = 256; dst = ws + 65536 + id*512; scale = 0.03125f; }
    else              { int id = f - 160; Mt = id >> 4; Kt = id & 15; src = W3; N = 64;  dst = ws + 81920 + id*512; }
#pragma unroll
    for (int j = 0; j < 8; j++){
      const int k = Kt*16 + 8*g + j;
      const int n = Mt*32 + col;
      float v = src[(size_t)k * N + n] * scale;
      __hip_bfloat16 h = __float2bfloat16(v);
      dst[l*8 + j] = *reinterpret_cast<short*>(&h);
    }
  } else {
    const int Mt = f - 192;
    short* dst = ws + 98304 + Mt*512;
    const int n = Mt*32 + col;
#pragma unroll
    for (int j = 0; j < 8; j++){
      const int k = 8*g + j;
      float v = 0.0f;
      if (k == 0) v = W1[(size_t)64*256 + n];   // t-coefficient row (unscaled)
      else if (k == 1) v = b1[n];               // b1 (unscaled)
      __hip_bfloat16 h = __float2bfloat16(v);
      dst[l*8 + j] = *reinterpret_cast<short*>(&h);
    }
  }
}

__global__ __launch_bounds__(1024) __attribute__((amdgpu_waves_per_eu(4)))
void flow_kernel(const float* __restrict__ x0,
                 const short* __restrict__ ws,
                 const float* __restrict__ b2,
                 const float* __restrict__ b3,
                 float* __restrict__ out){
  extern __shared__ short lds[];   // 160 KiB: W2 [0,65536), W1 [65536,81920)
  const int tid = threadIdx.x;
  {
    const int4* src = (const int4*)ws;
    int4* dst = (int4*)lds;
#pragma unroll
    for (int i = 0; i < 10; i++) dst[tid + i*1024] = src[tid + i*1024];
  }
  __syncthreads();

  const short* w2l = lds;
  const short* w1l = lds + 65536;
  const short* w3f = ws + 81920;
  const short* t1g = ws + 98304;

  const int lane = tid & 63;
  const int wv   = tid >> 6;
  const int g    = lane >> 5;
  const int m    = lane & 31;
  const int lf   = lane * 8;
  const float dt = 1.0f / 32.0f;

  const f32x16 zf = {0.f,0.f,0.f,0.f,0.f,0.f,0.f,0.f,0.f,0.f,0.f,0.f,0.f,0.f,0.f,0.f};

  const int rowbase = blockIdx.x * 512 + wv * 32;
  const float* xin = x0 + (size_t)(rowbase + m) * 64;

  // y state (= x/dt) in C layout: y[t][4q+i] = 32 * x[row m][32t + 8q + 4g + i]
  f32x16 y[2];
#pragma unroll
  for (int t = 0; t < 2; t++)
#pragma unroll
    for (int q = 0; q < 4; q++){
      f32x4 v = *(const f32x4*)(xin + t*32 + q*8 + g*4);
#pragma unroll
      for (int i = 0; i < 4; i++) y[t][q*4+i] = v[i] * 32.0f;
    }

  s16x8 b1f[4];
  c_to_b(y[0], b1f[0], b1f[1]);
  c_to_b(y[1], b1f[2], b1f[3]);

#pragma unroll 1
  for (int s = 0; s < 32; s++){
    const float tv = ((float)s + 0.5f) * (1.0f / 32.0f);
    s16x8 tf;   // B-frag [t,1,0...]
    { FragU o; o.u[0] = (g==0) ? cvtpk_bf16(tv, 1.0f) : 0u; o.u[1]=0u; o.u[2]=0u; o.u[3]=0u; tf = o.v; }

    // ---- y += b3 (start of this step's v accumulation) ----
#pragma unroll
    for (int t3 = 0; t3 < 2; t3++)
#pragma unroll
      for (int q = 0; q < 4; q++){
        f32x4 bv = *(const f32x4*)(b3 + t3*32 + q*8 + g*4);
#pragma unroll
        for (int i = 0; i < 4; i++) y[t3][q*4+i] += bv[i];
      }

    // ---- layer 1: h1 = silu(y@(dt*W1x) + t*W1t + b1); bias via t1f x tf ----
    s16x8 b2f[16];
#pragma unroll
    for (int Mt = 0; Mt < 8; Mt++){
      s16x8 t1a = *(const s16x8*)(t1g + Mt*512 + lf);
      f32x16 a = __builtin_amdgcn_mfma_f32_32x32x16_bf16(t1a, tf, zf, 0, 0, 0);
#pragma unroll
      for (int kt = 0; kt < 4; kt++){
        a = __builtin_amdgcn_mfma_f32_32x32x16_bf16(
              *(const s16x8*)(w1l + (Mt*4 + kt)*512 + lf), b1f[kt], a, 0, 0, 0);
      }
      silu16(a);
      c_to_b(a, b2f[2*Mt], b2f[2*Mt+1]);
    }

    // ---- layer 2 (+fused layer 3): y += silu(h1@W2+b2)@W3 ----
#pragma unroll
    for (int Mt = 0; Mt < 8; Mt++){
      // acc init from b2 (fp32 C-layout loads, L1-hot)
      f32x16 a;
#pragma unroll
      for (int q = 0; q < 4; q++){
        f32x4 bv = *(const f32x4*)(b2 + Mt*32 + q*8 + g*4);
#pragma unroll
        for (int i = 0; i < 4; i++) a[q*4+i] = bv[i];
      }
#pragma unroll
      for (int kt = 0; kt < 16; kt++){
        a = __builtin_amdgcn_mfma_f32_32x32x16_bf16(
              *(const s16x8*)(w2l + (Mt*16 + kt)*512 + lf), b2f[kt], a, 0, 0, 0);
      }
      // w3 frag loads issued before silu (silu covers the L1 latency)
      s16x8 w3a = *(const s16x8*)(w3f + (2*Mt     )*512 + lf);
      s16x8 w3b = *(const s16x8*)(w3f + (2*Mt + 1 )*512 + lf);
      s16x8 w3c = *(const s16x8*)(w3f + (16 + 2*Mt)*512 + lf);
      s16x8 w3d = *(const s16x8*)(w3f + (17 + 2*Mt)*512 + lf);
      silu16(a);
      s16x8 f0, f1;
      c_to_b(a, f0, f1);
      y[0] = __builtin_amdgcn_mfma_f32_32x32x16_bf16(w3a, f0, y[0], 0, 0, 0);
      y[1] = __builtin_amdgcn_mfma_f32_32x32x16_bf16(w3c, f0, y[1], 0, 0, 0);
      y[0] = __builtin_amdgcn_mfma_f32_32x32x16_bf16(w3b, f1, y[0], 0, 0, 0);
      y[1] = __builtin_amdgcn_mfma_f32_32x32x16_bf16(w3d, f1, y[1], 0, 0, 0);
    }

    // ---- rebuild layer-1 B-frags from y (W1x pre-scaled: no mul needed) ----
    c_to_b(y[0], b1f[0], b1f[1]);
    c_to_b(y[1], b1f[2], b1f[3]);
  }

  // out = dt * y
  float* xo = out + (size_t)(rowbase + m) * 64;
#pragma unroll
  for (int t = 0; t < 2; t++)
#pragma unroll
    for (int q = 0; q < 4; q++){
      f32x4 v;
#pragma unroll
      for (int i = 0; i < 4; i++) v[i] = y[t][q*4+i] * dt;
      *(f32x4*)(xo + t*32 + q*8 + g*4) = v;
    }
}

extern "C" void kernel_launch(void* const* d_in, const int* in_sizes, int n_in,
                              void* d_out, int out_size, void* d_ws, size_t ws_size,
                              hipStream_t stream){
  const float* x0 = (const float*)d_in[0];
  const float* W1 = (const float*)d_in[1];
  const float* b1 = (const float*)d_in[2];
  const float* W2 = (const float*)d_in[3];
  const float* b2 = (const float*)d_in[4];
  const float* W3 = (const float*)d_in[5];
  const float* b3 = (const float*)d_in[6];
  short* ws  = (short*)d_ws;
  float* out = (float*)d_out;
  (void)in_sizes; (void)n_in; (void)out_size; (void)ws_size;

  hipFuncSetAttribute((const void*)flow_kernel,
                      hipFuncAttributeMaxDynamicSharedMemorySize, 163840);

  setup_kernel<<<200, 64, 0, stream>>>(W1, b1, W2, W3, ws);
  flow_kernel<<<256, 1024, 163840, stream>>>(x0, ws, b2, b3, out);
}

// Round 9
// 2081.263 us; speedup vs baseline: 1.0187x; 1.0187x over previous
//
#include <hip/hip_runtime.h>
#include <hip/hip_bf16.h>

// Flow-matching MLP ODE, 32 midpoint-t Euler steps.
// R9 = R5/R2 512-thr 2-wave/SIMD structure (proven best) + latency fixes:
//  - W2 ONLY in LDS (128KB). W1/t1 frags from global (L1/L2-hot, separate
//    pipe from LDS, prefetchable via vmcnt).
//  - Explicit 1-tile lookahead for W1/t1 global frags (init'd, tail-clamped).
//  - 2-deep rotating register prefetch for W2 LDS frags (kills just-in-time
//    lgkmcnt stalls, the main idle-cycle suspect from R5 counters).
//  - y-state (R6-verified): y = x/dt lives in layer-3 accumulator; W1x frags
//    pre-scaled by dt=2^-5 (exact in bf16) so b1f = bf16(y) directly.
// Weights as A-frags (32x32x16 bf16), activations as B-frags; batch col =
// lane&31 lane-resident; C->B via v_cvt_pk_bf16_f32 + v_permlane32_swap_b32.

typedef __attribute__((ext_vector_type(8)))  short s16x8;   // 8 bf16 (4 VGPR)
typedef __attribute__((ext_vector_type(16))) float f32x16;  // MFMA acc
typedef __attribute__((ext_vector_type(4)))  float f32x4;

union FragU { s16x8 v; unsigned u[4]; };

__device__ __forceinline__ unsigned cvtpk_bf16(float lo, float hi){
  unsigned r;
  asm("v_cvt_pk_bf16_f32 %0, %1, %2" : "=v"(r) : "v"(lo), "v"(hi));
  return r;
}
__device__ __forceinline__ void plswap32(unsigned &a, unsigned &b){
  asm("v_permlane32_swap_b32 %0, %1" : "+v"(a), "+v"(b));
}

// C-tile (acc layout n=(r&3)+8*(r>>2)+4*g, m=l&31) -> two next-layer B-frags.
__device__ __forceinline__ void c_to_b(const f32x16 c, s16x8 &f0, s16x8 &f1){
  unsigned p0 = cvtpk_bf16(c[0],  c[1]);
  unsigned p1 = cvtpk_bf16(c[2],  c[3]);
  unsigned p2 = cvtpk_bf16(c[4],  c[5]);
  unsigned p3 = cvtpk_bf16(c[6],  c[7]);
  plswap32(p0, p2); plswap32(p1, p3);
  FragU a; a.u[0]=p0; a.u[1]=p1; a.u[2]=p2; a.u[3]=p3; f0 = a.v;
  unsigned q0 = cvtpk_bf16(c[8],  c[9]);
  unsigned q1 = cvtpk_bf16(c[10], c[11]);
  unsigned q2 = cvtpk_bf16(c[12], c[13]);
  plswap32(q0, q2);
  unsigned q1b = cvtpk_bf16(c[14], c[15]);
  plswap32(q1, q1b);
  FragU b; b.u[0]=q0; b.u[1]=q1; b.u[2]=q2; b.u[3]=q1b; f1 = b.v;
}

__device__ __forceinline__ void silu16(f32x16 &x){
#pragma unroll
  for (int i = 0; i < 16; i++){
    float e = __builtin_amdgcn_exp2f(x[i] * -1.44269504088896f); // exp(-x)
    x[i] = x[i] * __builtin_amdgcn_rcpf(1.0f + e);
  }
}

// ---- setup: pack weights + t1 frags (bf16 A-fragment images) into d_ws ----
// frag(Mt,Kt): lane l holds WT[Mt*32 + (l&31)][Kt*16 + 8*(l>>5) + j], j=0..7
// W1x frags PRE-SCALED by dt = 1/32 (exact exponent shift): kernel feeds
// y = x/dt directly as the layer-1 B-operand.
// ws shorts: [0,65536) W2 frags. [65536,81920) W1x*dt. [81920,98304) W3.
//            [98304,102400) t1-frags (k0=W1[64] t-row, k1=b1).
__global__ void setup_kernel(const float* __restrict__ W1,
                             const float* __restrict__ b1,
                             const float* __restrict__ W2,
                             const float* __restrict__ W3,
                             short* __restrict__ ws){
  const int f = blockIdx.x;
  const int l = threadIdx.x;
  const int g = l >> 5, col = l & 31;

  if (f < 192){
    const float* src; int N, Mt, Kt; short* dst; float scale = 1.0f;
    if (f < 128)      { Mt = f >> 4;      Kt = f & 15;       src = W2; N = 256; dst = ws + f*512; }
    else if (f < 160) { int id = f - 128; Mt = id >> 2; Kt = id & 3;  src = W1; N = 256; dst = ws + 65536 + id*512; scale = 0.03125f; }
    else              { int id = f - 160; Mt = id >> 4; Kt = id & 15; src = W3; N = 64;  dst = ws + 81920 + id*512; }
#pragma unroll
    for (int j = 0; j < 8; j++){
      const int k = Kt*16 + 8*g + j;
      const int n = Mt*32 + col;
      float v = src[(size_t)k * N + n] * scale;
      __hip_bfloat16 h = __float2bfloat16(v);
      dst[l*8 + j] = *reinterpret_cast<short*>(&h);
    }
  } else {
    const int Mt = f - 192;
    short* dst = ws + 98304 + Mt*512;
    const int n = Mt*32 + col;
#pragma unroll
    for (int j = 0; j < 8; j++){
      const int k = 8*g + j;
      float v = 0.0f;
      if (k == 0) v = W1[(size_t)64*256 + n];   // t-coefficient row (unscaled)
      else if (k == 1) v = b1[n];               // b1 (unscaled)
      __hip_bfloat16 h = __float2bfloat16(v);
      dst[l*8 + j] = *reinterpret_cast<short*>(&h);
    }
  }
}

__global__ __launch_bounds__(512) __attribute__((amdgpu_waves_per_eu(2, 2)))
void flow_kernel(const float* __restrict__ x0,
                 const short* __restrict__ ws,
                 const float* __restrict__ b2,
                 const float* __restrict__ b3,
                 float* __restrict__ out){
  extern __shared__ short lds[];   // 128 KiB: W2 frags only
  const int tid = threadIdx.x;
  {
    const int4* src = (const int4*)ws;
    int4* dst = (int4*)lds;
#pragma unroll
    for (int i = 0; i < 16; i++) dst[tid + i*512] = src[tid + i*512];
  }
  __syncthreads();

  const short* w2l = lds;
  const short* w1f = ws + 65536;
  const short* w3f = ws + 81920;
  const short* t1g = ws + 98304;

  const int lane = tid & 63;
  const int wv   = tid >> 6;
  const int g    = lane >> 5;
  const int m    = lane & 31;
  const int lf   = lane * 8;
  const float dt = 1.0f / 32.0f;

  const f32x16 zf = {0.f,0.f,0.f,0.f,0.f,0.f,0.f,0.f,0.f,0.f,0.f,0.f,0.f,0.f,0.f,0.f};

  for (int pass = 0; pass < 2; pass++){
    const int rowbase = blockIdx.x * 512 + (wv*2 + pass) * 32;
    const float* xin = x0 + (size_t)(rowbase + m) * 64;

    // y state (= x/dt) in C layout: y[t][4q+i] = 32 * x[row m][32t+8q+4g+i]
    f32x16 y[2];
#pragma unroll
    for (int t = 0; t < 2; t++)
#pragma unroll
      for (int q = 0; q < 4; q++){
        f32x4 v = *(const f32x4*)(xin + t*32 + q*8 + g*4);
#pragma unroll
        for (int i = 0; i < 4; i++) y[t][q*4+i] = v[i] * 32.0f;
      }

    s16x8 b1f[4];
    c_to_b(y[0], b1f[0], b1f[1]);
    c_to_b(y[1], b1f[2], b1f[3]);

#pragma unroll 1
    for (int s = 0; s < 32; s++){
      const float tv = ((float)s + 0.5f) * (1.0f / 32.0f);
      s16x8 tf;   // B-frag [t,1,0...]
      { FragU o; o.u[0] = (g==0) ? cvtpk_bf16(tv, 1.0f) : 0u; o.u[1]=0u; o.u[2]=0u; o.u[3]=0u; tf = o.v; }

      // ---- y += b3 (start of this step's v accumulation) ----
#pragma unroll
      for (int t3 = 0; t3 < 2; t3++)
#pragma unroll
        for (int q = 0; q < 4; q++){
          f32x4 bv = *(const f32x4*)(b3 + t3*32 + q*8 + g*4);
#pragma unroll
          for (int i = 0; i < 4; i++) y[t3][q*4+i] += bv[i];
        }

      // ---- layer 1 (W1/t1 from GLOBAL, 1-tile lookahead) ----
      s16x8 b2f[16];
      s16x8 t1c  = *(const s16x8*)(t1g + 0*512 + lf);
      s16x8 w1c0 = *(const s16x8*)(w1f + 0*512 + lf);
      s16x8 w1c1 = *(const s16x8*)(w1f + 1*512 + lf);
      s16x8 w1c2 = *(const s16x8*)(w1f + 2*512 + lf);
      s16x8 w1c3 = *(const s16x8*)(w1f + 3*512 + lf);
#pragma unroll
      for (int Mt = 0; Mt < 8; Mt++){
        const int nx = (Mt < 7) ? (Mt + 1) : 7;   // tail-clamped (defined)
        s16x8 t1n  = *(const s16x8*)(t1g + nx*512 + lf);
        s16x8 w1n0 = *(const s16x8*)(w1f + (nx*4+0)*512 + lf);
        s16x8 w1n1 = *(const s16x8*)(w1f + (nx*4+1)*512 + lf);
        s16x8 w1n2 = *(const s16x8*)(w1f + (nx*4+2)*512 + lf);
        s16x8 w1n3 = *(const s16x8*)(w1f + (nx*4+3)*512 + lf);

        f32x16 a = __builtin_amdgcn_mfma_f32_32x32x16_bf16(t1c, tf, zf, 0, 0, 0);
        a = __builtin_amdgcn_mfma_f32_32x32x16_bf16(w1c0, b1f[0], a, 0, 0, 0);
        a = __builtin_amdgcn_mfma_f32_32x32x16_bf16(w1c1, b1f[1], a, 0, 0, 0);
        a = __builtin_amdgcn_mfma_f32_32x32x16_bf16(w1c2, b1f[2], a, 0, 0, 0);
        a = __builtin_amdgcn_mfma_f32_32x32x16_bf16(w1c3, b1f[3], a, 0, 0, 0);
        silu16(a);
        c_to_b(a, b2f[2*Mt], b2f[2*Mt+1]);
        t1c = t1n; w1c0 = w1n0; w1c1 = w1n1; w1c2 = w1n2; w1c3 = w1n3;
      }

      // ---- layer 2 (+fused layer 3): y += silu(h1@W2+b2)@W3 ----
#pragma unroll
      for (int Mt = 0; Mt < 8; Mt++){
        // acc init from b2 (fp32 C-layout loads, L1-hot)
        f32x16 a;
#pragma unroll
        for (int q = 0; q < 4; q++){
          f32x4 bv = *(const f32x4*)(b2 + Mt*32 + q*8 + g*4);
#pragma unroll
          for (int i = 0; i < 4; i++) a[q*4+i] = bv[i];
        }
        // 2-deep rotating LDS prefetch of W2 frags
        s16x8 wa = *(const s16x8*)(w2l + (Mt*16 + 0)*512 + lf);
        s16x8 wb = *(const s16x8*)(w2l + (Mt*16 + 1)*512 + lf);
#pragma unroll
        for (int kt = 0; kt < 16; kt++){
          s16x8 wn = (kt < 14) ? *(const s16x8*)(w2l + (Mt*16 + kt + 2)*512 + lf)
                               : wa;   // tail dummy (defined)
          a = __builtin_amdgcn_mfma_f32_32x32x16_bf16(wa, b2f[kt], a, 0, 0, 0);
          wa = wb; wb = wn;
        }
        // w3 frag loads issued before silu (silu covers the latency)
        s16x8 w3a = *(const s16x8*)(w3f + (2*Mt     )*512 + lf);
        s16x8 w3b = *(const s16x8*)(w3f + (2*Mt + 1 )*512 + lf);
        s16x8 w3c = *(const s16x8*)(w3f + (16 + 2*Mt)*512 + lf);
        s16x8 w3d = *(const s16x8*)(w3f + (17 + 2*Mt)*512 + lf);
        silu16(a);
        s16x8 f0, f1;
        c_to_b(a, f0, f1);
        y[0] = __builtin_amdgcn_mfma_f32_32x32x16_bf16(w3a, f0, y[0], 0, 0, 0);
        y[1] = __builtin_amdgcn_mfma_f32_32x32x16_bf16(w3c, f0, y[1], 0, 0, 0);
        y[0] = __builtin_amdgcn_mfma_f32_32x32x16_bf16(w3b, f1, y[0], 0, 0, 0);
        y[1] = __builtin_amdgcn_mfma_f32_32x32x16_bf16(w3d, f1, y[1], 0, 0, 0);
      }

      // ---- rebuild layer-1 B-frags from y (W1x pre-scaled: no mul) ----
      c_to_b(y[0], b1f[0], b1f[1]);
      c_to_b(y[1], b1f[2], b1f[3]);
    }

    // out = dt * y
    float* xo = out + (size_t)(rowbase + m) * 64;
#pragma unroll
    for (int t = 0; t < 2; t++)
#pragma unroll
      for (int q = 0; q < 4; q++){
        f32x4 v;
#pragma unroll
        for (int i = 0; i < 4; i++) v[i] = y[t][q*4+i] * dt;
        *(f32x4*)(xo + t*32 + q*8 + g*4) = v;
      }
  }
}

extern "C" void kernel_launch(void* const* d_in, const int* in_sizes, int n_in,
                              void* d_out, int out_size, void* d_ws, size_t ws_size,
                              hipStream_t stream){
  const float* x0 = (const float*)d_in[0];
  const float* W1 = (const float*)d_in[1];
  const float* b1 = (const float*)d_in[2];
  const float* W2 = (const float*)d_in[3];
  const float* b2 = (const float*)d_in[4];
  const float* W3 = (const float*)d_in[5];
  const float* b3 = (const float*)d_in[6];
  short* ws  = (short*)d_ws;
  float* out = (float*)d_out;
  (void)in_sizes; (void)n_in; (void)out_size; (void)ws_size;

  hipFuncSetAttribute((const void*)flow_kernel,
                      hipFuncAttributeMaxDynamicSharedMemorySize, 131072);

  setup_kernel<<<200, 64, 0, stream>>>(W1, b1, W2, W3, ws);
  flow_kernel<<<256, 512, 131072, stream>>>(x0, ws, b2, b3, out);
}